// Round 6
// baseline (48.525 us; speedup 1.0000x reference)
//
#include <hip/hip_runtime.h>
#include <hip/hip_cooperative_groups.h>
#include <math.h>
#include <float.h>

namespace cg = cooperative_groups;

#define NMAX 512
#define TILE 16
#define FDIV(a,b) __fdividef((a),(b))

// ws SoA planes (stride NMAX floats):
//  [0]=mx [1]=my [2]=q00 [3]=qs [4]=q11  (conic pre-scaled by -0.5; qs = merged cross term)
//  [5]=O [6]=c0 [7]=c1 [8]=c2
//  [9]=bnd (int: xmin | xmax<<8 | ymin<<16 | ymax<<24)
//  [10]=key (uint: order-preserving depth bits)

__global__ __launch_bounds__(512) void fused_coop(
    const float* __restrict__ mu, const float* __restrict__ scales,
    const float* __restrict__ quats, const float* __restrict__ cols,
    const float* __restrict__ opcs, const float* __restrict__ vm,
    const int* __restrict__ focal_p, const int* __restrict__ H_p,
    const int* __restrict__ W_p, float* __restrict__ ws,
    float* __restrict__ out, int N, int ntx)
{
    __shared__ int s_bc[8];
    __shared__ unsigned long long s_lk[NMAX];   // (key<<32)|idx, compacted
    __shared__ int s_ord[NMAX];                 // sorted gaussian indices
    __shared__ float s_mx[NMAX], s_my[NMAX];
    __shared__ float s_q00[NMAX], s_qs[NMAX], s_q11[NMAX];
    __shared__ float s_O[NMAX], s_c0[NMAX], s_c1[NMAX], s_c2[NMAX];
    __shared__ float s_pr[256], s_pg[256], s_pb[256];

    const int lt  = threadIdx.x;     // 0..511
    const int bid = blockIdx.x;

    // ================= phase A: per-Gaussian prep, once grid-wide =================
    if (lt < 2) {
        for (int g = bid * 2 + lt; g < N; g += gridDim.x * 2) {
            const int   Wi = W_p[0], Hi = H_p[0];
            const float fx = (float)focal_p[0];
            const float fy = fx;
            const float Wf = (float)Wi, Hf = (float)Hi;
            const float cxf = (float)((double)Wi / 2.0);
            const float cyf = (float)((double)Hi / 2.0);
            const float sxc = (float)(2.0 * (double)fx / (double)Wi);
            const float syc = (float)(2.0 * (double)fy / (double)Hi);
            const float dc1 = (float)((10.0 + 0.01) / (10.0 - 0.01));
            const float dc2 = (float)(-2.0 * 10.0 * 0.01 / (10.0 - 0.01));
            const int Wt = Wi / TILE, Ht = Hi / TILE;

            const float m0 = mu[3*g], m1 = mu[3*g+1], m2 = mu[3*g+2];
            const float t0 = vm[0]*m0  + vm[1]*m1  + vm[2]*m2  + vm[3];
            const float t1 = vm[4]*m0  + vm[5]*m1  + vm[6]*m2  + vm[7];
            const float t2 = vm[8]*m0  + vm[9]*m1  + vm[10]*m2 + vm[11];
            const float t3 = vm[12]*m0 + vm[13]*m1 + vm[14]*m2 + vm[15];

            const float depth = dc1 * t2 + dc2 * t3;
            unsigned int ub = __float_as_uint(depth);
            ub = (ub & 0x80000000u) ? ~ub : (ub | 0x80000000u);

            const float mx = FDIV(Wf * (sxc * t0), t2) * 0.5f + cxf;
            const float my = FDIV(Hf * (syc * t1), t2) * 0.5f + cyf;

            // quaternion -> R (reference's exact formulas incl. its r11/r20 quirks)
            const float4 q = ((const float4*)quats)[g];
            const float qx = q.x, qy = q.y, qz = q.z, qw = q.w;
            const float R00 = 1.0f - 2.0f*(qy*qy + qz*qz);
            const float R01 = 2.0f*(qx*qy - qw*qz);
            const float R02 = 2.0f*(qx*qz + qw*qy);
            const float R10 = 2.0f*(qx*qy + qw*qz);
            const float R11 = 1.0f - 2.0f*(qx*qx - qz*qz);
            const float R12 = 2.0f*(qy*qz - qw*qx);
            const float R20 = 2.0f*(qx*qz + qw*qy);
            const float R21 = 2.0f*(qy*qz + qw*qx);
            const float R22 = 1.0f - 2.0f*(qx*qx + qy*qy);

            const float s0 = scales[3*g], s1 = scales[3*g+1], s2 = scales[3*g+2];
            const float A00 = R00*s0, A01 = R01*s1, A02 = R02*s2;
            const float A10 = R10*s0, A11 = R11*s1, A12 = R12*s2;
            const float A20 = R20*s0, A21 = R21*s1, A22 = R22*s2;
            const float S00 = A00*A00 + A01*A01 + A02*A02;
            const float S01 = A00*A10 + A01*A11 + A02*A12;
            const float S02 = A00*A20 + A01*A21 + A02*A22;
            const float S11 = A10*A10 + A11*A11 + A12*A12;
            const float S12 = A10*A20 + A11*A21 + A12*A22;
            const float S22 = A20*A20 + A21*A21 + A22*A22;

            const float tz = t2;
            const float J00 = FDIV(fx, tz);
            const float J02 = FDIV(-fx * t0, tz * tz);
            const float J11 = FDIV(fy, tz);
            const float J12 = FDIV(-fy * t1, tz * tz);
            const float M00 = J00*vm[0] + J02*vm[8];
            const float M01 = J00*vm[1] + J02*vm[9];
            const float M02 = J00*vm[2] + J02*vm[10];
            const float M10 = J11*vm[4] + J12*vm[8];
            const float M11 = J11*vm[5] + J12*vm[9];
            const float M12 = J11*vm[6] + J12*vm[10];
            const float T00 = M00*S00 + M01*S01 + M02*S02;
            const float T01 = M00*S01 + M01*S11 + M02*S12;
            const float T02 = M00*S02 + M01*S12 + M02*S22;
            const float T10 = M10*S00 + M11*S01 + M12*S02;
            const float T11 = M10*S01 + M11*S11 + M12*S12;
            const float T12 = M10*S02 + M11*S12 + M12*S22;
            const float a   = T00*M00 + T01*M01 + T02*M02;
            const float b   = T00*M10 + T01*M11 + T02*M12;
            const float c10 = T10*M00 + T11*M01 + T12*M02;
            const float d   = T10*M10 + T11*M11 + T12*M12;

            const float Aev = sqrtf(a*a - 2.0f*a*d + 4.0f*b*b + d*d);
            const float Bev = a + d;
            const float l1 = 0.5f * (Aev + Bev);
            const float l2 = 0.5f * (Bev - Aev);
            const float r1 = (l1 > 0.0f) ? 3.0f * sqrtf(l1) : NAN;
            const float r2 = (l2 > 0.0f) ? 3.0f * sqrtf(l2) : NAN;

            // cos/sin of atan2(l1-a, b) computed algebraically
            float cth, sth;
            if (b != 0.0f) {
                const float yv = l1 - a;
                const float h  = sqrtf(b*b + yv*yv);     // > 0 since b != 0
                cth = FDIV(b,  h);
                sth = FDIV(yv, h);
            } else if (a >= d) {
                cth = -4.371139e-8f;   // cosf(pi/2 as float)
                sth = 1.0f;
            } else {
                cth = 1.0f;
                sth = 0.0f;
            }

            const float crx[4] = { mx - r1, mx + r1, mx + r1, mx - r1 };
            const float cry[4] = { my + r2, my + r2, my - r2, my - r2 };
            const float bmx = (((crx[0] + crx[1]) + crx[2]) + crx[3]) * 0.25f;
            const float bmy = (((cry[0] + cry[1]) + cry[2]) + cry[3]) * 0.25f;

            float xmn = FLT_MAX, xmxv = -FLT_MAX, ymn = FLT_MAX, ymxv = -FLT_MAX;
            #pragma unroll
            for (int k = 0; k < 4; ++k) {
                const float ox = crx[k] - bmx, oy = cry[k] - bmy;
                float bx = (cth*ox + (-sth)*oy) + bmx;
                float by = (sth*ox + cth*oy) + bmy;
                if (isnan(bx)) bx = -1.0f;
                if (isnan(by)) by = -1.0f;
                xmn = fminf(xmn, bx); xmxv = fmaxf(xmxv, bx);
                ymn = fminf(ymn, by); ymxv = fmaxf(ymxv, by);
            }
            const int xmin = (int)fminf(fmaxf(floorf(xmn  * 0.0625f), 0.0f), (float)(Wt - 1));
            const int xmax = (int)fminf(fmaxf(ceilf (xmxv * 0.0625f), 0.0f), (float)(Wt - 1));
            const int ymin = (int)fminf(fmaxf(floorf(ymn  * 0.0625f), 0.0f), (float)(Ht - 1));
            const int ymax = (int)fminf(fmaxf(ceilf (ymxv * 0.0625f), 0.0f), (float)(Ht - 1));

            const float e = 1e-06f;
            const float det = (a + e) * (d + e) - b * c10;
            const float idet = FDIV(1.0f, det);

            const float op  = opcs[g];
            const float sg1 = FDIV(1.0f, 1.0f + __expf(-op));

            ws[0*NMAX + g] = mx;
            ws[1*NMAX + g] = my;
            ws[2*NMAX + g] = -0.5f * (d + e) * idet;       // -0.5*i00
            ws[3*NMAX + g] =  0.5f * (b + c10) * idet;     // -0.5*(i01+i10)
            ws[4*NMAX + g] = -0.5f * (a + e) * idet;       // -0.5*i11
            ws[5*NMAX + g] = FDIV(1.0f, 1.0f + __expf(-sg1));
            ws[6*NMAX + g] = fminf(fmaxf(cols[3*g    ], 1e-04f), 1.0f);
            ws[7*NMAX + g] = fminf(fmaxf(cols[3*g + 1], 1e-04f), 1.0f);
            ws[8*NMAX + g] = fminf(fmaxf(cols[3*g + 2], 1e-04f), 1.0f);
            ((int*)ws)[9*NMAX + g] = xmin | (xmax << 8) | (ymin << 16) | (ymax << 24);
            ((unsigned int*)ws)[10*NMAX + g] = ub;
        }
    }

    cg::this_grid().sync();

    // ================= phase B: per-tile compact + sort + composite =================
    const int tx = bid % ntx, ty = bid / ntx;
    const int lane = lt & 63, w = lt >> 6;

    bool covered = false;
    if (lt < N) {
        const int bnd = ((const int*)ws)[9*NMAX + lt];
        const int xmin =  bnd        & 255;
        const int xmax = (bnd >> 8)  & 255;
        const int ymin = (bnd >> 16) & 255;
        const int ymax = (bnd >> 24) & 255;
        covered = (tx >= xmin) & (tx <= xmax) & (ty >= ymin) & (ty <= ymax);
    }
    const unsigned long long word = __ballot(covered);
    if (lane == 0) s_bc[w] = __popcll(word);
    __syncthreads();

    int base = 0, M = 0;
    #pragma unroll
    for (int i = 0; i < 8; ++i) {
        const int c = s_bc[i];
        if (i < w) base += c;
        M += c;
    }
    if (covered) {
        const int rank = base + __popcll(word & ((1ull << lane) - 1ull));
        const unsigned int key = ((const unsigned int*)ws)[10*NMAX + lt];
        s_lk[rank] = ((unsigned long long)key << 32) | (unsigned int)lt;
    }
    __syncthreads();

    // deterministic rank sort by (key, idx)
    for (int t = lt; t < M; t += 512) {
        const unsigned long long mine = s_lk[t];
        int rank = 0;
        for (int s = 0; s < M; ++s) rank += (s_lk[s] < mine) ? 1 : 0;
        s_ord[rank] = (int)(mine & 0xFFFFFFFFu);
    }
    __syncthreads();

    // stage covered records into LDS in sorted order
    for (int t = lt; t < M; t += 512) {
        const int g = s_ord[t];
        s_mx [t] = ws[0*NMAX + g];
        s_my [t] = ws[1*NMAX + g];
        s_q00[t] = ws[2*NMAX + g];
        s_qs [t] = ws[3*NMAX + g];
        s_q11[t] = ws[4*NMAX + g];
        s_O  [t] = ws[5*NMAX + g];
        s_c0 [t] = ws[6*NMAX + g];
        s_c1 [t] = ws[7*NMAX + g];
        s_c2 [t] = ws[8*NMAX + g];
    }
    __syncthreads();

    // split alpha compositing (front half / back half per pixel)
    const int p  = lt & 255;
    const int hv = lt >> 8;
    const int W  = ntx * TILE;
    const int px = tx * TILE + (p & 15);
    const int py = ty * TILE + (p >> 4);
    const float fpx = (float)px, fpy = (float)py;

    const int Mh = (M + 1) >> 1;
    const int j0 = hv ? Mh : 0;
    const int j1 = hv ? M  : Mh;

    float Tt = 1.0f, rr = 0.0f, gg = 0.0f, bb = 0.0f;
    for (int j = j0; j < j1; ++j) {
        const float dx = fpx - s_mx[j];
        const float dy = fpy - s_my[j];
        const float qv = s_q00[j]*dx*dx + s_qs[j]*(dx*dy) + s_q11[j]*dy*dy;
        float Pg = __expf(qv);                   // conic pre-scaled by -0.5
        if (Pg != Pg) Pg = 0.0f;                 // nan_to_num
        float alpha = s_O[j] * Pg;
        alpha = (alpha < 0.001f) ? 0.0f : fminf(alpha, 0.99f);  // branchless mask
        const float wgt = alpha * Tt;
        rr = fmaf(wgt, s_c0[j], rr);
        gg = fmaf(wgt, s_c1[j], gg);
        bb = fmaf(wgt, s_c2[j], bb);
        Tt = fmaf(-alpha, Tt, Tt);
    }

    if (hv == 1) { s_pr[p] = rr; s_pg[p] = gg; s_pb[p] = bb; }
    __syncthreads();

    if (hv == 0) {
        rr = fmaf(Tt, s_pr[p], rr);
        gg = fmaf(Tt, s_pg[p], gg);
        bb = fmaf(Tt, s_pb[p], bb);

        const int o = (py * W + px) * 3;
        if (M > 0) {
            out[o    ] = fminf(fmaxf(rr, 1e-04f), 1.0f);
            out[o + 1] = fminf(fmaxf(gg, 1e-04f), 1.0f);
            out[o + 2] = fminf(fmaxf(bb, 1e-04f), 1.0f);
        } else {
            out[o] = 0.0f; out[o + 1] = 0.0f; out[o + 2] = 0.0f;
        }
    }
}

extern "C" void kernel_launch(void* const* d_in, const int* in_sizes, int n_in,
                              void* d_out, int out_size, void* d_ws, size_t ws_size,
                              hipStream_t stream) {
    const float* mu     = (const float*)d_in[0];
    const float* scales = (const float*)d_in[1];
    const float* quats  = (const float*)d_in[2];
    const float* cols   = (const float*)d_in[3];
    const float* opcs   = (const float*)d_in[4];
    const float* vm     = (const float*)d_in[5];
    // d_in[6] = gt (unused by forward)
    const int* focal_p  = (const int*)d_in[7];
    const int* H_p      = (const int*)d_in[8];
    const int* W_p      = (const int*)d_in[9];

    int N = in_sizes[4];                    // opcs count = number of Gaussians
    const int HW = out_size / 3;
    int W = (int)(sqrt((double)HW) + 0.5);  // 256 for this problem
    int H = HW / W;
    int ntx = W / TILE, nty = H / TILE;

    float* ws   = (float*)d_ws;
    float* outp = (float*)d_out;

    void* args[] = { (void*)&mu, (void*)&scales, (void*)&quats, (void*)&cols,
                     (void*)&opcs, (void*)&vm, (void*)&focal_p, (void*)&H_p,
                     (void*)&W_p, (void*)&ws, (void*)&outp, (void*)&N, (void*)&ntx };

    hipLaunchCooperativeKernel((void*)fused_coop, dim3(ntx * nty), dim3(512),
                               args, 0, stream);
}

// Round 7
// 16.259 us; speedup vs baseline: 2.9845x; 2.9845x over previous
//
#include <hip/hip_runtime.h>
#include <math.h>
#include <float.h>

#define NMAX 512
#define TILE 16
#define FDIV(a,b) __fdividef((a),(b))

// Single fused kernel: one block (512 threads) per 16x16 tile.
// Phase 1: thread g preps Gaussian g -> LDS planes (indexed by g); coverage
//          flag + depth key stay in registers.
// Phase 2: ballot-compaction (deterministic, g-ordered) -> rank sort by
//          (depth key, idx)  == global stable argsort restricted to subset.
// Phase 3: split alpha compositing (2 threads/pixel, front/back halves),
//          reading records through the broadcast indirection s_ord[j].
__global__ __launch_bounds__(512) void fused_kernel(
    const float* __restrict__ mu, const float* __restrict__ scales,
    const float* __restrict__ quats, const float* __restrict__ cols,
    const float* __restrict__ opcs, const float* __restrict__ vm,
    const int* __restrict__ focal_p, const int* __restrict__ H_p,
    const int* __restrict__ W_p, float* __restrict__ out, int N)
{
    __shared__ float s_mx[NMAX], s_my[NMAX];
    __shared__ float s_q00[NMAX], s_qs[NMAX], s_q11[NMAX];  // conic * -0.5, cross merged
    __shared__ float s_O[NMAX], s_c0[NMAX], s_c1[NMAX], s_c2[NMAX];
    __shared__ unsigned long long s_lk[NMAX];   // (key<<32)|idx, compacted
    __shared__ int s_ord[NMAX];                 // sorted gaussian indices
    __shared__ float s_pr[256], s_pg[256], s_pb[256];
    __shared__ int s_bc[8];

    const int lt = threadIdx.x;          // 0..511
    const int lane = lt & 63, w = lt >> 6;
    const int tx = blockIdx.x, ty = blockIdx.y;

    const int   Wi = W_p[0], Hi = H_p[0];
    const float fx = (float)focal_p[0];
    const float fy = fx;
    const float Wf = (float)Wi, Hf = (float)Hi;
    const float cxf = (float)((double)Wi / 2.0);
    const float cyf = (float)((double)Hi / 2.0);
    const float sxc = (float)(2.0 * (double)fx / (double)Wi);
    const float syc = (float)(2.0 * (double)fy / (double)Hi);
    const float dc1 = (float)((10.0 + 0.01) / (10.0 - 0.01));
    const float dc2 = (float)(-2.0 * 10.0 * 0.01 / (10.0 - 0.01));
    const int Wt = Wi / TILE, Ht = Hi / TILE;

    // ---------------- phase 1: prep (1 Gaussian per thread) ----------------
    bool covered = false;
    unsigned int key = 0;
    const int g = lt;
    if (g < N) {
        const float m0 = mu[3*g], m1 = mu[3*g+1], m2 = mu[3*g+2];
        const float t0 = vm[0]*m0  + vm[1]*m1  + vm[2]*m2  + vm[3];
        const float t1 = vm[4]*m0  + vm[5]*m1  + vm[6]*m2  + vm[7];
        const float t2 = vm[8]*m0  + vm[9]*m1  + vm[10]*m2 + vm[11];
        const float t3 = vm[12]*m0 + vm[13]*m1 + vm[14]*m2 + vm[15];

        const float depth = dc1 * t2 + dc2 * t3;
        unsigned int ub = __float_as_uint(depth);
        key = (ub & 0x80000000u) ? ~ub : (ub | 0x80000000u);

        const float mx = FDIV(Wf * (sxc * t0), t2) * 0.5f + cxf;
        const float my = FDIV(Hf * (syc * t1), t2) * 0.5f + cyf;

        // quaternion -> R (reference's exact formulas incl. its r11/r20 quirks)
        const float4 q = ((const float4*)quats)[g];
        const float qx = q.x, qy = q.y, qz = q.z, qw = q.w;
        const float R00 = 1.0f - 2.0f*(qy*qy + qz*qz);
        const float R01 = 2.0f*(qx*qy - qw*qz);
        const float R02 = 2.0f*(qx*qz + qw*qy);
        const float R10 = 2.0f*(qx*qy + qw*qz);
        const float R11 = 1.0f - 2.0f*(qx*qx - qz*qz);
        const float R12 = 2.0f*(qy*qz - qw*qx);
        const float R20 = 2.0f*(qx*qz + qw*qy);
        const float R21 = 2.0f*(qy*qz + qw*qx);
        const float R22 = 1.0f - 2.0f*(qx*qx + qy*qy);

        const float s0 = scales[3*g], s1 = scales[3*g+1], s2 = scales[3*g+2];
        const float A00 = R00*s0, A01 = R01*s1, A02 = R02*s2;
        const float A10 = R10*s0, A11 = R11*s1, A12 = R12*s2;
        const float A20 = R20*s0, A21 = R21*s1, A22 = R22*s2;
        const float S00 = A00*A00 + A01*A01 + A02*A02;
        const float S01 = A00*A10 + A01*A11 + A02*A12;
        const float S02 = A00*A20 + A01*A21 + A02*A22;
        const float S11 = A10*A10 + A11*A11 + A12*A12;
        const float S12 = A10*A20 + A11*A21 + A12*A22;
        const float S22 = A20*A20 + A21*A21 + A22*A22;

        const float tz = t2;
        const float J00 = FDIV(fx, tz);
        const float J02 = FDIV(-fx * t0, tz * tz);
        const float J11 = FDIV(fy, tz);
        const float J12 = FDIV(-fy * t1, tz * tz);
        const float M00 = J00*vm[0] + J02*vm[8];
        const float M01 = J00*vm[1] + J02*vm[9];
        const float M02 = J00*vm[2] + J02*vm[10];
        const float M10 = J11*vm[4] + J12*vm[8];
        const float M11 = J11*vm[5] + J12*vm[9];
        const float M12 = J11*vm[6] + J12*vm[10];
        const float T00 = M00*S00 + M01*S01 + M02*S02;
        const float T01 = M00*S01 + M01*S11 + M02*S12;
        const float T02 = M00*S02 + M01*S12 + M02*S22;
        const float T10 = M10*S00 + M11*S01 + M12*S02;
        const float T11 = M10*S01 + M11*S11 + M12*S12;
        const float T12 = M10*S02 + M11*S12 + M12*S22;
        const float a   = T00*M00 + T01*M01 + T02*M02;
        const float b   = T00*M10 + T01*M11 + T02*M12;
        const float c10 = T10*M00 + T11*M01 + T12*M02;
        const float d   = T10*M10 + T11*M11 + T12*M12;

        const float Aev = sqrtf(a*a - 2.0f*a*d + 4.0f*b*b + d*d);
        const float Bev = a + d;
        const float l1 = 0.5f * (Aev + Bev);
        const float l2 = 0.5f * (Bev - Aev);
        const float r1 = (l1 > 0.0f) ? 3.0f * sqrtf(l1) : NAN;
        const float r2 = (l2 > 0.0f) ? 3.0f * sqrtf(l2) : NAN;

        // cos/sin of atan2(l1-a, b) computed algebraically
        float cth, sth;
        if (b != 0.0f) {
            const float yv = l1 - a;
            const float h  = sqrtf(b*b + yv*yv);
            cth = FDIV(b,  h);
            sth = FDIV(yv, h);
        } else if (a >= d) {
            cth = -4.371139e-8f;   // cosf(pi/2 as float)
            sth = 1.0f;
        } else {
            cth = 1.0f;
            sth = 0.0f;
        }

        // closed-form rotated bbox (bit-faithful to the 4-corner min/max):
        // corners x in {u,v}, y in {r_,s_}; rotation is separable in max/min.
        const float u  = mx - r1, v  = mx + r1;
        const float r_ = my + r2, s_ = my - r2;
        const float bmx = (((u + v) + v) + u) * 0.25f;
        const float bmy = (((r_ + r_) + s_) + s_) * 0.25f;
        const float pxo = u - bmx, qxo = v - bmx;
        const float ryo = r_ - bmy, syo = s_ - bmy;

        const float Axp = cth * pxo, Axq = cth * qxo;
        const float Bxr = (-sth) * ryo, Bxs = (-sth) * syo;
        float xmn  = (fminf(Axp, Axq) + fminf(Bxr, Bxs)) + bmx;
        float xmxv = (fmaxf(Axp, Axq) + fmaxf(Bxr, Bxs)) + bmx;
        const float Ayp = sth * pxo, Ayq = sth * qxo;
        const float Byr = cth * ryo, Bys = cth * syo;
        float ymn  = (fminf(Ayp, Ayq) + fminf(Byr, Bys)) + bmy;
        float ymxv = (fmaxf(Ayp, Ayq) + fmaxf(Byr, Bys)) + bmy;
        if (isnan(xmxv)) { xmn = -1.0f; xmxv = -1.0f; }   // all-x-corners NaN
        if (isnan(ymxv)) { ymn = -1.0f; ymxv = -1.0f; }   // all-y-corners NaN

        const int xmin = (int)fminf(fmaxf(floorf(xmn  * 0.0625f), 0.0f), (float)(Wt - 1));
        const int xmax = (int)fminf(fmaxf(ceilf (xmxv * 0.0625f), 0.0f), (float)(Wt - 1));
        const int ymin = (int)fminf(fmaxf(floorf(ymn  * 0.0625f), 0.0f), (float)(Ht - 1));
        const int ymax = (int)fminf(fmaxf(ceilf (ymxv * 0.0625f), 0.0f), (float)(Ht - 1));

        const float e = 1e-06f;
        const float det = (a + e) * (d + e) - b * c10;
        const float idet = FDIV(1.0f, det);

        const float op  = opcs[g];
        const float sg1 = FDIV(1.0f, 1.0f + __expf(-op));

        s_mx [g] = mx;
        s_my [g] = my;
        s_q00[g] = -0.5f * (d + e) * idet;     // -0.5*i00
        s_qs [g] =  0.5f * (b + c10) * idet;   // -0.5*(i01+i10)
        s_q11[g] = -0.5f * (a + e) * idet;     // -0.5*i11
        s_O  [g] = FDIV(1.0f, 1.0f + __expf(-sg1));
        s_c0 [g] = fminf(fmaxf(cols[3*g    ], 1e-04f), 1.0f);
        s_c1 [g] = fminf(fmaxf(cols[3*g + 1], 1e-04f), 1.0f);
        s_c2 [g] = fminf(fmaxf(cols[3*g + 2], 1e-04f), 1.0f);

        covered = (tx >= xmin) & (tx <= xmax) & (ty >= ymin) & (ty <= ymax);
    }

    // ---------------- phase 2: ballot compaction + rank sort ----------------
    const unsigned long long word = __ballot(covered);
    if (lane == 0) s_bc[w] = __popcll(word);
    __syncthreads();

    int base = 0, M = 0;
    #pragma unroll
    for (int i = 0; i < 8; ++i) {
        const int c = s_bc[i];
        if (i < w) base += c;
        M += c;
    }
    if (covered) {
        const int rank = base + __popcll(word & ((1ull << lane) - 1ull));
        s_lk[rank] = ((unsigned long long)key << 32) | (unsigned int)g;
    }
    __syncthreads();

    for (int t = lt; t < M; t += 512) {
        const unsigned long long mine = s_lk[t];
        int rank = 0;
        for (int s = 0; s < M; ++s) rank += (s_lk[s] < mine) ? 1 : 0;
        s_ord[rank] = (int)(mine & 0xFFFFFFFFu);
    }
    __syncthreads();

    // ---------------- phase 3: split alpha compositing ----------------
    const int p  = lt & 255;
    const int hv = lt >> 8;
    const int W  = gridDim.x * TILE;
    const int px = tx * TILE + (p & 15);
    const int py = ty * TILE + (p >> 4);
    const float fpx = (float)px, fpy = (float)py;

    const int Mh = (M + 1) >> 1;
    const int j0 = hv ? Mh : 0;
    const int j1 = hv ? M  : Mh;

    float Tt = 1.0f, rr = 0.0f, gg = 0.0f, bb = 0.0f;
    for (int j = j0; j < j1; ++j) {
        const int n = s_ord[j];                  // broadcast indirection
        const float dx = fpx - s_mx[n];
        const float dy = fpy - s_my[n];
        const float qv = s_q00[n]*dx*dx + s_qs[n]*(dx*dy) + s_q11[n]*dy*dy;
        float Pg = __expf(qv);                   // conic pre-scaled by -0.5
        if (Pg != Pg) Pg = 0.0f;                 // nan_to_num
        float alpha = s_O[n] * Pg;
        alpha = (alpha < 0.001f) ? 0.0f : fminf(alpha, 0.99f);
        const float wgt = alpha * Tt;
        rr = fmaf(wgt, s_c0[n], rr);
        gg = fmaf(wgt, s_c1[n], gg);
        bb = fmaf(wgt, s_c2[n], bb);
        Tt = fmaf(-alpha, Tt, Tt);
    }

    if (hv == 1) { s_pr[p] = rr; s_pg[p] = gg; s_pb[p] = bb; }
    __syncthreads();

    if (hv == 0) {
        rr = fmaf(Tt, s_pr[p], rr);
        gg = fmaf(Tt, s_pg[p], gg);
        bb = fmaf(Tt, s_pb[p], bb);

        const int o = (py * W + px) * 3;
        if (M > 0) {
            out[o    ] = fminf(fmaxf(rr, 1e-04f), 1.0f);
            out[o + 1] = fminf(fmaxf(gg, 1e-04f), 1.0f);
            out[o + 2] = fminf(fmaxf(bb, 1e-04f), 1.0f);
        } else {
            out[o] = 0.0f; out[o + 1] = 0.0f; out[o + 2] = 0.0f;
        }
    }
}

extern "C" void kernel_launch(void* const* d_in, const int* in_sizes, int n_in,
                              void* d_out, int out_size, void* d_ws, size_t ws_size,
                              hipStream_t stream) {
    const float* mu     = (const float*)d_in[0];
    const float* scales = (const float*)d_in[1];
    const float* quats  = (const float*)d_in[2];
    const float* cols   = (const float*)d_in[3];
    const float* opcs   = (const float*)d_in[4];
    const float* vm     = (const float*)d_in[5];
    // d_in[6] = gt (unused by forward)
    const int* focal_p  = (const int*)d_in[7];
    const int* H_p      = (const int*)d_in[8];
    const int* W_p      = (const int*)d_in[9];

    const int N = in_sizes[4];              // opcs count = number of Gaussians
    const int HW = out_size / 3;
    int W = (int)(sqrt((double)HW) + 0.5);  // 256 for this problem
    int H = HW / W;

    dim3 grid(W / TILE, H / TILE), block(512);
    fused_kernel<<<grid, block, 0, stream>>>(mu, scales, quats, cols, opcs, vm,
                                             focal_p, H_p, W_p, (float*)d_out, N);
}